// Round 23
// baseline (186.336 us; speedup 1.0000x reference)
//
#include <hip/hip_runtime.h>
#include <hip/hip_fp16.h>

// r22 base (57.1 us best) + phase-1 restructure: stencil reads p DIRECTLY from
// global (L2-resident via XCD swizzle) as 12 coalesced scalars per chunk per
// thread, assembled into channel-quads in registers. Phase 1 now has ZERO LDS
// ops and ZERO barriers (was 17) -- waves free-run; total barriers 25 -> 8.
// DPP wave-shift stencil, f16 keep, R[128][13] reduce, 2-wide XOR-swizzled
// exchange tiles (all r21/r22-verified) unchanged.

__device__ __forceinline__ float dot4acc(float4 a, float4 b, float acc) {
    acc = fmaf(a.x, b.x, acc);
    acc = fmaf(a.y, b.y, acc);
    acc = fmaf(a.z, b.z, acc);
    acc = fmaf(a.w, b.w, acc);
    return acc;
}

__device__ __forceinline__ float wshr1(float x) {
    return __int_as_float(__builtin_amdgcn_update_dpp(
        0, __float_as_int(x), 0x138, 0xF, 0xF, true));   // WAVE_SHR1
}
__device__ __forceinline__ float wshl1(float x) {
    return __int_as_float(__builtin_amdgcn_update_dpp(
        0, __float_as_int(x), 0x130, 0xF, 0xF, true));   // WAVE_SHL1
}
__device__ __forceinline__ float4 f4shr(float4 v) {
    return make_float4(wshr1(v.x), wshr1(v.y), wshr1(v.z), wshr1(v.w));
}
__device__ __forceinline__ float4 f4shl(float4 v) {
    return make_float4(wshl1(v.x), wshl1(v.y), wshl1(v.z), wshl1(v.w));
}

__global__ __launch_bounds__(512) void bcim_fused(const float* __restrict__ p,
                                                  float* __restrict__ out) {
    __shared__ float shbuf[9216];   // R[128][13] reduce; phase3: 2 x T[128][36]
    __shared__ float invL[192];
    __shared__ float simv[128];

    const int tid = threadIdx.x;
    const int d  = blockIdx.x;
    const int b  = (d & 7) * 32 + ((d >> 3) & 31);   // image -> fixed XCD (r20-verified)
    const int r0 = (d >> 8) << 2;                    // strip
    const float* __restrict__ pb = p + (size_t)b * 131072;

    // ---- mapping (r21-verified): wave = one full row ----
    const int w     = tid & 31;          // lane bits 0-4
    const int chalf = (tid >> 5) & 1;    // lane bit 5
    const int cgrp  = (tid >> 6) & 1;    // wave bit 0
    const int h     = tid >> 7;          // wave bits 1-2
    const int pos   = h * 32 + w;
    const int wm    = (w > 0) ? w - 1 : 0;
    const int wp    = (w < 31) ? w + 1 : 31;

    // rows (padded h .. h+2 -> global r0-1+h .. r0+1+h); OOB -> zero quads
    const int gT = r0 - 1 + h;
    const int gB2 = gT + 2;
    const bool okT = ((unsigned)gT  < 32u);   // wave-uniform
    const bool okB = ((unsigned)gB2 < 32u);
    const int oT = (okT ? gT : 0) * 32;
    const int oC = (gT + 1) * 32;
    const int oB = (okB ? gB2 : 0) * 32;

    const int cbase = cgrp * 64 + chalf * 4;
    const float* __restrict__ pw = pb + w;
    const float4 z4 = make_float4(0.f, 0.f, 0.f, 0.f);

    #define LOADQ(QT, QC, QB, STP) {                                                \
        const float* bp = pw + (cbase + (STP) * 8) * 1024;                          \
        QC = make_float4(bp[oC], bp[1024 + oC], bp[2048 + oC], bp[3072 + oC]);      \
        QT = okT ? make_float4(bp[oT], bp[1024 + oT], bp[2048 + oT], bp[3072 + oT]) \
                 : z4;                                                              \
        QB = okB ? make_float4(bp[oB], bp[1024 + oB], bp[2048 + oB], bp[3072 + oB]) \
                 : z4; }

    float4 cT, cC, cB, nT, nC, nB;
    LOADQ(cT, cC, cB, 0)

    float s0=0.f,s1=0.f,s2=0.f,s3=0.f,s4=0.f,s5=0.f,s6=0.f,s7=0.f,s8=0.f,hn=0.f;
    __half2 kA[8], kB[8];

    #define CHUNK(QT, QC, QB, NT, NC, NB, STP) {                                    \
        if ((STP) < 7) LOADQ(NT, NC, NB, (STP) + 1)                                 \
        kA[STP] = __floats2half2_rn(QC.x, QC.y);                                    \
        kB[STP] = __floats2half2_rn(QC.z, QC.w);                                    \
        s0 = dot4acc(QC, f4shr(QT), s0);                                            \
        s1 = dot4acc(QC, QT,        s1);                                            \
        s2 = dot4acc(QC, f4shl(QT), s2);                                            \
        if (h == 0) hn = dot4acc(QT, QT, hn);                                       \
        s3 = dot4acc(QC, f4shr(QC), s3);                                            \
        s4 = dot4acc(QC, QC,        s4);                                            \
        s5 = dot4acc(QC, f4shl(QC), s5);                                            \
        s6 = dot4acc(QC, f4shr(QB), s6);                                            \
        s7 = dot4acc(QC, QB,        s7);                                            \
        s8 = dot4acc(QC, f4shl(QB), s8);                                            \
        if (h == 3) hn = dot4acc(QB, QB, hn); }

    CHUNK(cT, cC, cB, nT, nC, nB, 0)
    CHUNK(nT, nC, nB, cT, cC, cB, 1)
    CHUNK(cT, cC, cB, nT, nC, nB, 2)
    CHUNK(nT, nC, nB, cT, cC, cB, 3)
    CHUNK(cT, cC, cB, nT, nC, nB, 4)
    CHUNK(nT, nC, nB, cT, cC, cB, 5)
    CHUNK(cT, cC, cB, nT, nC, nB, 6)
    CHUNK(nT, nC, nB, cT, cC, cB, 7)
    #undef CHUNK
    #undef LOADQ

    // ---- chalf reduce (in-wave, lane^32) ----
    s0 += __shfl_xor(s0, 32); s1 += __shfl_xor(s1, 32); s2 += __shfl_xor(s2, 32);
    s3 += __shfl_xor(s3, 32); s4 += __shfl_xor(s4, 32); s5 += __shfl_xor(s5, 32);
    s6 += __shfl_xor(s6, 32); s7 += __shfl_xor(s7, 32); s8 += __shfl_xor(s8, 32);
    hn += __shfl_xor(hn, 32);

    // ---- cgrp reduce via R[128][13] (stride 13: conflict-free) ----
    float* R = shbuf;
    if (cgrp == 1 && chalf == 0) {
        const int rb = pos * 13;
        R[rb+0]=s0; R[rb+1]=s1; R[rb+2]=s2; R[rb+3]=s3; R[rb+4]=s4;
        R[rb+5]=s5; R[rb+6]=s6; R[rb+7]=s7; R[rb+8]=s8; R[rb+9]=hn;
    }
    __syncthreads();
    if (cgrp == 0) {
        const int rb = pos * 13;
        s0 += R[rb+0]; s1 += R[rb+1]; s2 += R[rb+2]; s3 += R[rb+3]; s4 += R[rb+4];
        s5 += R[rb+5]; s6 += R[rb+6]; s7 += R[rb+7]; s8 += R[rb+8]; hn += R[rb+9];
        if (chalf == 0) {
            invL[(h + 1) * 32 + w] = (s4 > 0.f) ? (1.0f / sqrtf(s4)) : 0.f;
            if (h == 0) invL[w]       = (hn > 0.f) ? (1.0f / sqrtf(hn)) : 0.f;
            if (h == 3) invL[160 + w] = (hn > 0.f) ? (1.0f / sqrtf(hn)) : 0.f;
        }
    }
    __syncthreads();
    if (cgrp == 0 && chalf == 0) {
        const float mL = (w > 0)  ? 1.f : 0.f;
        const float mR = (w < 31) ? 1.f : 0.f;
        const float* iT = invL + h * 32;
        const float* iM = iT + 32;
        const float* iB = iM + 32;
        float acc;
        acc = s0 * (iT[wm] * mL);
        acc = fmaf(s1, iT[w],       acc);
        acc = fmaf(s2, iT[wp] * mR, acc);
        acc = fmaf(s3, iM[wm] * mL, acc);
        acc = fmaf(s4, iM[w],       acc);
        acc = fmaf(s5, iM[wp] * mR, acc);
        acc = fmaf(s6, iB[wm] * mL, acc);
        acc = fmaf(s7, iB[w],       acc);
        acc = fmaf(s8, iB[wp] * mR, acc);
        simv[pos] = acc * iM[w] * (1.0f / 9.0f);
    }
    __syncthreads();
    const float simreg = simv[pos];
    __syncthreads();   // simv/R consumed before tile overwrite

    // ---- phase 3 (r22-verified): 2-wide XOR-swizzled exchange tiles ----
    const int xsw = (w >> 2) & 7;
    #pragma unroll
    for (int cbp = 0; cbp < 2; ++cbp) {
        float* Tg = shbuf + cgrp * 4608;
        #pragma unroll
        for (int m = 0; m < 4; ++m) {
            const int ki = cbp * 4 + m;
            const float2 lo = __half22float2(kA[ki]);
            const float2 hi = __half22float2(kB[ki]);
            float4 kk = make_float4(lo.x, lo.y, hi.x, hi.y);
            kk.x *= simreg; kk.y *= simreg; kk.z *= simreg; kk.w *= simreg;
            const int sp2 = ((m * 2 + chalf) ^ xsw) << 1;
            const int base = pos * 36;
            *(float2*)&Tg[base + sp2]      = make_float2(kk.x, kk.z);   // t = 0
            *(float2*)&Tg[base + 16 + sp2] = make_float2(kk.y, kk.w);   // t = 1
        }
        __syncthreads();
        #pragma unroll
        for (int stp2 = 0; stp2 < 4; ++stp2) {
            const int flat = stp2 * 512 + tid;       // 0..2047
            const int qf = flat & 3;
            const int t  = (flat >> 2) & 1;
            const int pp = (flat >> 3) & 127;
            const int cbsel = flat >> 10;            // tile select
            const int hh = pp >> 5;
            const int ww = pp & 31;
            const int xr = (ww >> 2) & 7;
            const int p0 = (qf << 1) ^ xr;           // physical f2 slot of pair0
            float4 o = *(const float4*)&shbuf[cbsel * 4608 + pp * 36 + t * 16 +
                                              ((p0 & ~1) << 1)];
            if (p0 & 1) o = make_float4(o.z, o.w, o.x, o.y);
            const int cb = cbp + (cbsel << 1);
            *(float4*)(out + (size_t)b * 131072 + (size_t)t * 65536 +
                       (size_t)(r0 + hh) * 2048 + ww * 64 + cb * 16 + qf * 4) = o;
        }
        __syncthreads();
    }
}

extern "C" void kernel_launch(void* const* d_in, const int* in_sizes, int n_in,
                              void* d_out, int out_size, void* d_ws, size_t ws_size,
                              hipStream_t stream) {
    const float* p = (const float*)d_in[0];
    float* out = (float*)d_out;
    bcim_fused<<<dim3(2048), dim3(512), 0, stream>>>(p, out);
    (void)in_sizes; (void)n_in; (void)out_size; (void)d_ws; (void)ws_size;
}

// Round 24
// 56.885 us; speedup vs baseline: 3.2757x; 3.2757x over previous
//
#include <hip/hip_runtime.h>
#include <hip/hip_fp16.h>

// REVERT to r22 (57.1 us verified best). r23's LDS-free phase 1 spilled
// (VGPR 128, WRITE 311 MB). This kernel: XCD-locality block swizzle, 8-chunk
// LDS-staged phase 1 with wave-row DPP stencil (3 ds_read_b128/chunk), f16
// keep, shfl chalf-reduce + R[128][13] cgrp-reduce, 2-wide XOR-swizzled
// stride-36 exchange tiles for the channel-transposed coalesced output.

__device__ __forceinline__ float dot4acc(float4 a, float4 b, float acc) {
    acc = fmaf(a.x, b.x, acc);
    acc = fmaf(a.y, b.y, acc);
    acc = fmaf(a.z, b.z, acc);
    acc = fmaf(a.w, b.w, acc);
    return acc;
}

__device__ __forceinline__ float wshr1(float x) {
    return __int_as_float(__builtin_amdgcn_update_dpp(
        0, __float_as_int(x), 0x138, 0xF, 0xF, true));   // WAVE_SHR1
}
__device__ __forceinline__ float wshl1(float x) {
    return __int_as_float(__builtin_amdgcn_update_dpp(
        0, __float_as_int(x), 0x130, 0xF, 0xF, true));   // WAVE_SHL1
}
__device__ __forceinline__ float4 f4shr(float4 v) {
    return make_float4(wshr1(v.x), wshr1(v.y), wshr1(v.z), wshr1(v.w));
}
__device__ __forceinline__ float4 f4shl(float4 v) {
    return make_float4(wshl1(v.x), wshl1(v.y), wshl1(v.z), wshl1(v.w));
}

__global__ __launch_bounds__(512) void bcim_fused(const float* __restrict__ p,
                                                  float* __restrict__ out) {
    __shared__ float shbuf[9216];   // phase1: 2 slabs x 1536; R[128][13]; phase3: 2 x T[128][36]
    __shared__ float invL[192];
    __shared__ float simv[128];

    const int tid = threadIdx.x;
    const int d  = blockIdx.x;
    const int b  = (d & 7) * 32 + ((d >> 3) & 31);   // image -> fixed XCD
    const int r0 = (d >> 8) << 2;                    // strip
    const float* __restrict__ pb = p + (size_t)b * 131072;
    float* slab = shbuf;

    // ---- loader slots ----
    const int s0wq = tid & 7, s0c = (tid >> 3) & 7, s0r = (tid >> 6) % 6, s0s = tid / 384;
    const int i1   = 512 + tid;
    const int s1wq = i1 & 7,  s1c = (i1 >> 3) & 7,  s1r = (i1 >> 6) % 6;
    const int g0row = r0 - 1 + s0r;
    const int g1row = r0 - 1 + s1r;
    const bool ok0 = ((unsigned)g0row < 32u);
    const bool ok1 = (tid < 256) && ((unsigned)g1row < 32u);
    int w0Off[4], w1Off[4];
    {
        const int ch0 = s0c >> 2, ci0 = s0c & 3;
        const int ch1 = s1c >> 2, ci1 = s1c & 3;
        #pragma unroll
        for (int j = 0; j < 4; ++j) {
            const int u0 = ((s0wq << 3) + (j << 1) + ch0) ^ s0wq;
            const int u1 = ((s1wq << 3) + (j << 1) + ch1) ^ s1wq;
            w0Off[j] = s0s * 1536 + s0r * 256 + u0 * 4 + ci0;
            w1Off[j] = 1536 + s1r * 256 + u1 * 4 + ci1;
        }
    }
    const int gB0 = (s0s * 64 + s0c) * 1024 + g0row * 32 + s0wq * 4;
    const int gB1 = (64 + s1c) * 1024 + g1row * 32 + s1wq * 4;

    // ---- stencil mapping: wave = one full row ----
    const int w     = tid & 31;
    const int chalf = (tid >> 5) & 1;
    const int cgrp  = (tid >> 6) & 1;
    const int h     = tid >> 7;
    const int pos   = h * 32 + w;
    const int wm    = (w > 0) ? w - 1 : 0;
    const int wp    = (w < 31) ? w + 1 : 31;
    const int uc    = (w * 2 + chalf) ^ (w >> 2);
    const float4* spC = (const float4*)(slab + cgrp * 1536);

    float4 st0 = make_float4(0.f, 0.f, 0.f, 0.f), st1 = st0;
    if (ok0) st0 = *(const float4*)(pb + gB0);
    if (ok1) st1 = *(const float4*)(pb + gB1);

    float s0=0.f,s1=0.f,s2=0.f,s3=0.f,s4=0.f,s5=0.f,s6=0.f,s7=0.f,s8=0.f,hn=0.f;
    __half2 kA[8], kB[8];

    #pragma unroll
    for (int stp = 0; stp < 8; ++stp) {
        slab[w0Off[0]] = st0.x; slab[w0Off[1]] = st0.y;
        slab[w0Off[2]] = st0.z; slab[w0Off[3]] = st0.w;
        if (tid < 256) {
            slab[w1Off[0]] = st1.x; slab[w1Off[1]] = st1.y;
            slab[w1Off[2]] = st1.z; slab[w1Off[3]] = st1.w;
        }
        __syncthreads();
        if (stp < 7) {
            if (ok0) st0 = *(const float4*)(pb + (stp + 1) * 8192 + gB0);
            if (ok1) st1 = *(const float4*)(pb + (stp + 1) * 8192 + gB1);
        }
        {
            const float4 qt = spC[(h + 0) * 64 + uc];
            const float4 qc = spC[(h + 1) * 64 + uc];
            const float4 qb = spC[(h + 2) * 64 + uc];
            kA[stp] = __floats2half2_rn(qc.x, qc.y);
            kB[stp] = __floats2half2_rn(qc.z, qc.w);
            s0 = dot4acc(qc, f4shr(qt), s0);
            s1 = dot4acc(qc, qt,        s1);
            s2 = dot4acc(qc, f4shl(qt), s2);
            if (h == 0) hn = dot4acc(qt, qt, hn);
            s3 = dot4acc(qc, f4shr(qc), s3);
            s4 = dot4acc(qc, qc,        s4);
            s5 = dot4acc(qc, f4shl(qc), s5);
            s6 = dot4acc(qc, f4shr(qb), s6);
            s7 = dot4acc(qc, qb,        s7);
            s8 = dot4acc(qc, f4shl(qb), s8);
            if (h == 3) hn = dot4acc(qb, qb, hn);
        }
        __syncthreads();
    }

    // ---- chalf reduce (in-wave, lane^32) ----
    s0 += __shfl_xor(s0, 32); s1 += __shfl_xor(s1, 32); s2 += __shfl_xor(s2, 32);
    s3 += __shfl_xor(s3, 32); s4 += __shfl_xor(s4, 32); s5 += __shfl_xor(s5, 32);
    s6 += __shfl_xor(s6, 32); s7 += __shfl_xor(s7, 32); s8 += __shfl_xor(s8, 32);
    hn += __shfl_xor(hn, 32);

    // ---- cgrp reduce via R[128][13] ----
    float* R = shbuf;
    if (cgrp == 1 && chalf == 0) {
        const int rb = pos * 13;
        R[rb+0]=s0; R[rb+1]=s1; R[rb+2]=s2; R[rb+3]=s3; R[rb+4]=s4;
        R[rb+5]=s5; R[rb+6]=s6; R[rb+7]=s7; R[rb+8]=s8; R[rb+9]=hn;
    }
    __syncthreads();
    if (cgrp == 0) {
        const int rb = pos * 13;
        s0 += R[rb+0]; s1 += R[rb+1]; s2 += R[rb+2]; s3 += R[rb+3]; s4 += R[rb+4];
        s5 += R[rb+5]; s6 += R[rb+6]; s7 += R[rb+7]; s8 += R[rb+8]; hn += R[rb+9];
        if (chalf == 0) {
            invL[(h + 1) * 32 + w] = (s4 > 0.f) ? (1.0f / sqrtf(s4)) : 0.f;
            if (h == 0) invL[w]       = (hn > 0.f) ? (1.0f / sqrtf(hn)) : 0.f;
            if (h == 3) invL[160 + w] = (hn > 0.f) ? (1.0f / sqrtf(hn)) : 0.f;
        }
    }
    __syncthreads();
    if (cgrp == 0 && chalf == 0) {
        const float mL = (w > 0)  ? 1.f : 0.f;
        const float mR = (w < 31) ? 1.f : 0.f;
        const float* iT = invL + h * 32;
        const float* iM = iT + 32;
        const float* iB = iM + 32;
        float acc;
        acc = s0 * (iT[wm] * mL);
        acc = fmaf(s1, iT[w],       acc);
        acc = fmaf(s2, iT[wp] * mR, acc);
        acc = fmaf(s3, iM[wm] * mL, acc);
        acc = fmaf(s4, iM[w],       acc);
        acc = fmaf(s5, iM[wp] * mR, acc);
        acc = fmaf(s6, iB[wm] * mL, acc);
        acc = fmaf(s7, iB[w],       acc);
        acc = fmaf(s8, iB[wp] * mR, acc);
        simv[pos] = acc * iM[w] * (1.0f / 9.0f);
    }
    __syncthreads();
    const float simreg = simv[pos];
    __syncthreads();   // simv/R consumed before tile overwrite

    // ---- phase 3: 2-wide XOR-swizzled exchange tiles ----
    const int xsw = (w >> 2) & 7;
    #pragma unroll
    for (int cbp = 0; cbp < 2; ++cbp) {
        float* Tg = shbuf + cgrp * 4608;
        #pragma unroll
        for (int m = 0; m < 4; ++m) {
            const int ki = cbp * 4 + m;
            const float2 lo = __half22float2(kA[ki]);
            const float2 hi = __half22float2(kB[ki]);
            float4 kk = make_float4(lo.x, lo.y, hi.x, hi.y);
            kk.x *= simreg; kk.y *= simreg; kk.z *= simreg; kk.w *= simreg;
            const int sp2 = ((m * 2 + chalf) ^ xsw) << 1;
            const int base = pos * 36;
            *(float2*)&Tg[base + sp2]      = make_float2(kk.x, kk.z);   // t = 0
            *(float2*)&Tg[base + 16 + sp2] = make_float2(kk.y, kk.w);   // t = 1
        }
        __syncthreads();
        #pragma unroll
        for (int stp2 = 0; stp2 < 4; ++stp2) {
            const int flat = stp2 * 512 + tid;       // 0..2047
            const int qf = flat & 3;
            const int t  = (flat >> 2) & 1;
            const int pp = (flat >> 3) & 127;
            const int cbsel = flat >> 10;            // tile select
            const int hh = pp >> 5;
            const int ww = pp & 31;
            const int xr = (ww >> 2) & 7;
            const int p0 = (qf << 1) ^ xr;           // physical f2 slot of pair0
            float4 o = *(const float4*)&shbuf[cbsel * 4608 + pp * 36 + t * 16 +
                                              ((p0 & ~1) << 1)];
            if (p0 & 1) o = make_float4(o.z, o.w, o.x, o.y);
            const int cb = cbp + (cbsel << 1);
            *(float4*)(out + (size_t)b * 131072 + (size_t)t * 65536 +
                       (size_t)(r0 + hh) * 2048 + ww * 64 + cb * 16 + qf * 4) = o;
        }
        __syncthreads();
    }
}

extern "C" void kernel_launch(void* const* d_in, const int* in_sizes, int n_in,
                              void* d_out, int out_size, void* d_ws, size_t ws_size,
                              hipStream_t stream) {
    const float* p = (const float*)d_in[0];
    float* out = (float*)d_out;
    bcim_fused<<<dim3(2048), dim3(512), 0, stream>>>(p, out);
    (void)in_sizes; (void)n_in; (void)out_size; (void)d_ws; (void)ws_size;
}

// Round 25
// 55.036 us; speedup vs baseline: 3.3857x; 1.0336x over previous
//
#include <hip/hip_runtime.h>
#include <hip/hip_fp16.h>

// r24/r22 base (56.9 us best) + phase-3 re-partition: the two exchange rounds
// split by t-PLANE (not q-half). Round t: every thread writes all 8 of its ki
// f2s (t-component) into its cgrp tile (16 f2 slots/row); readers then cover
// q 0..63 contiguously -> each (t,pos) is one 256B segment and each wave's 16
// stores form a fully contiguous 1KB span (perfect coalescing; r22's 64B
// interleaved segments caused WRITE 155 vs 134 MB ideal). Same LDS, same 4
// barriers, same total LDS ops. All else r24-exact.

__device__ __forceinline__ float dot4acc(float4 a, float4 b, float acc) {
    acc = fmaf(a.x, b.x, acc);
    acc = fmaf(a.y, b.y, acc);
    acc = fmaf(a.z, b.z, acc);
    acc = fmaf(a.w, b.w, acc);
    return acc;
}

__device__ __forceinline__ float wshr1(float x) {
    return __int_as_float(__builtin_amdgcn_update_dpp(
        0, __float_as_int(x), 0x138, 0xF, 0xF, true));   // WAVE_SHR1
}
__device__ __forceinline__ float wshl1(float x) {
    return __int_as_float(__builtin_amdgcn_update_dpp(
        0, __float_as_int(x), 0x130, 0xF, 0xF, true));   // WAVE_SHL1
}
__device__ __forceinline__ float4 f4shr(float4 v) {
    return make_float4(wshr1(v.x), wshr1(v.y), wshr1(v.z), wshr1(v.w));
}
__device__ __forceinline__ float4 f4shl(float4 v) {
    return make_float4(wshl1(v.x), wshl1(v.y), wshl1(v.z), wshl1(v.w));
}

__global__ __launch_bounds__(512) void bcim_fused(const float* __restrict__ p,
                                                  float* __restrict__ out) {
    __shared__ float shbuf[9216];   // phase1: 2 slabs x 1536; R[128][13]; phase3: 2 x T[128][36]
    __shared__ float invL[192];
    __shared__ float simv[128];

    const int tid = threadIdx.x;
    const int d  = blockIdx.x;
    const int b  = (d & 7) * 32 + ((d >> 3) & 31);   // image -> fixed XCD
    const int r0 = (d >> 8) << 2;                    // strip
    const float* __restrict__ pb = p + (size_t)b * 131072;
    float* slab = shbuf;

    // ---- loader slots ----
    const int s0wq = tid & 7, s0c = (tid >> 3) & 7, s0r = (tid >> 6) % 6, s0s = tid / 384;
    const int i1   = 512 + tid;
    const int s1wq = i1 & 7,  s1c = (i1 >> 3) & 7,  s1r = (i1 >> 6) % 6;
    const int g0row = r0 - 1 + s0r;
    const int g1row = r0 - 1 + s1r;
    const bool ok0 = ((unsigned)g0row < 32u);
    const bool ok1 = (tid < 256) && ((unsigned)g1row < 32u);
    int w0Off[4], w1Off[4];
    {
        const int ch0 = s0c >> 2, ci0 = s0c & 3;
        const int ch1 = s1c >> 2, ci1 = s1c & 3;
        #pragma unroll
        for (int j = 0; j < 4; ++j) {
            const int u0 = ((s0wq << 3) + (j << 1) + ch0) ^ s0wq;
            const int u1 = ((s1wq << 3) + (j << 1) + ch1) ^ s1wq;
            w0Off[j] = s0s * 1536 + s0r * 256 + u0 * 4 + ci0;
            w1Off[j] = 1536 + s1r * 256 + u1 * 4 + ci1;
        }
    }
    const int gB0 = (s0s * 64 + s0c) * 1024 + g0row * 32 + s0wq * 4;
    const int gB1 = (64 + s1c) * 1024 + g1row * 32 + s1wq * 4;

    // ---- stencil mapping: wave = one full row ----
    const int w     = tid & 31;
    const int chalf = (tid >> 5) & 1;
    const int cgrp  = (tid >> 6) & 1;
    const int h     = tid >> 7;
    const int pos   = h * 32 + w;
    const int wm    = (w > 0) ? w - 1 : 0;
    const int wp    = (w < 31) ? w + 1 : 31;
    const int uc    = (w * 2 + chalf) ^ (w >> 2);
    const float4* spC = (const float4*)(slab + cgrp * 1536);

    float4 st0 = make_float4(0.f, 0.f, 0.f, 0.f), st1 = st0;
    if (ok0) st0 = *(const float4*)(pb + gB0);
    if (ok1) st1 = *(const float4*)(pb + gB1);

    float s0=0.f,s1=0.f,s2=0.f,s3=0.f,s4=0.f,s5=0.f,s6=0.f,s7=0.f,s8=0.f,hn=0.f;
    __half2 kA[8], kB[8];

    #pragma unroll
    for (int stp = 0; stp < 8; ++stp) {
        slab[w0Off[0]] = st0.x; slab[w0Off[1]] = st0.y;
        slab[w0Off[2]] = st0.z; slab[w0Off[3]] = st0.w;
        if (tid < 256) {
            slab[w1Off[0]] = st1.x; slab[w1Off[1]] = st1.y;
            slab[w1Off[2]] = st1.z; slab[w1Off[3]] = st1.w;
        }
        __syncthreads();
        if (stp < 7) {
            if (ok0) st0 = *(const float4*)(pb + (stp + 1) * 8192 + gB0);
            if (ok1) st1 = *(const float4*)(pb + (stp + 1) * 8192 + gB1);
        }
        {
            const float4 qt = spC[(h + 0) * 64 + uc];
            const float4 qc = spC[(h + 1) * 64 + uc];
            const float4 qb = spC[(h + 2) * 64 + uc];
            kA[stp] = __floats2half2_rn(qc.x, qc.y);
            kB[stp] = __floats2half2_rn(qc.z, qc.w);
            s0 = dot4acc(qc, f4shr(qt), s0);
            s1 = dot4acc(qc, qt,        s1);
            s2 = dot4acc(qc, f4shl(qt), s2);
            if (h == 0) hn = dot4acc(qt, qt, hn);
            s3 = dot4acc(qc, f4shr(qc), s3);
            s4 = dot4acc(qc, qc,        s4);
            s5 = dot4acc(qc, f4shl(qc), s5);
            s6 = dot4acc(qc, f4shr(qb), s6);
            s7 = dot4acc(qc, qb,        s7);
            s8 = dot4acc(qc, f4shl(qb), s8);
            if (h == 3) hn = dot4acc(qb, qb, hn);
        }
        __syncthreads();
    }

    // ---- chalf reduce (in-wave, lane^32) ----
    s0 += __shfl_xor(s0, 32); s1 += __shfl_xor(s1, 32); s2 += __shfl_xor(s2, 32);
    s3 += __shfl_xor(s3, 32); s4 += __shfl_xor(s4, 32); s5 += __shfl_xor(s5, 32);
    s6 += __shfl_xor(s6, 32); s7 += __shfl_xor(s7, 32); s8 += __shfl_xor(s8, 32);
    hn += __shfl_xor(hn, 32);

    // ---- cgrp reduce via R[128][13] ----
    float* R = shbuf;
    if (cgrp == 1 && chalf == 0) {
        const int rb = pos * 13;
        R[rb+0]=s0; R[rb+1]=s1; R[rb+2]=s2; R[rb+3]=s3; R[rb+4]=s4;
        R[rb+5]=s5; R[rb+6]=s6; R[rb+7]=s7; R[rb+8]=s8; R[rb+9]=hn;
    }
    __syncthreads();
    if (cgrp == 0) {
        const int rb = pos * 13;
        s0 += R[rb+0]; s1 += R[rb+1]; s2 += R[rb+2]; s3 += R[rb+3]; s4 += R[rb+4];
        s5 += R[rb+5]; s6 += R[rb+6]; s7 += R[rb+7]; s8 += R[rb+8]; hn += R[rb+9];
        if (chalf == 0) {
            invL[(h + 1) * 32 + w] = (s4 > 0.f) ? (1.0f / sqrtf(s4)) : 0.f;
            if (h == 0) invL[w]       = (hn > 0.f) ? (1.0f / sqrtf(hn)) : 0.f;
            if (h == 3) invL[160 + w] = (hn > 0.f) ? (1.0f / sqrtf(hn)) : 0.f;
        }
    }
    __syncthreads();
    if (cgrp == 0 && chalf == 0) {
        const float mL = (w > 0)  ? 1.f : 0.f;
        const float mR = (w < 31) ? 1.f : 0.f;
        const float* iT = invL + h * 32;
        const float* iM = iT + 32;
        const float* iB = iM + 32;
        float acc;
        acc = s0 * (iT[wm] * mL);
        acc = fmaf(s1, iT[w],       acc);
        acc = fmaf(s2, iT[wp] * mR, acc);
        acc = fmaf(s3, iM[wm] * mL, acc);
        acc = fmaf(s4, iM[w],       acc);
        acc = fmaf(s5, iM[wp] * mR, acc);
        acc = fmaf(s6, iB[wm] * mL, acc);
        acc = fmaf(s7, iB[w],       acc);
        acc = fmaf(s8, iB[wp] * mR, acc);
        simv[pos] = acc * iM[w] * (1.0f / 9.0f);
    }
    __syncthreads();
    const float simreg = simv[pos];
    __syncthreads();   // simv/R consumed before tile overwrite

    // ---- phase 3: t-plane rounds, contiguous 256B/(t,pos) output ----
    // Round t: writer lane stores all 8 ki f2s (t-component) into its cgrp
    // tile; f2 slot s = ki*2+chalf (holds q-local {2s,2s+1}), physical s^xsw.
    // Reader: qf16 = q-quad 0..15, tile = qf16>>3, u = qf16&7; one f4 read
    // (+half-swap if needed), stored at q-contiguous addresses: each wave's
    // 16 stores span 1KB contiguous.
    const int xsw = (w >> 2) & 7;
    #pragma unroll
    for (int t = 0; t < 2; ++t) {
        float* Tg = shbuf + cgrp * 4608;
        #pragma unroll
        for (int ki = 0; ki < 8; ++ki) {
            const float2 lo = __half22float2(kA[ki]);   // j0, j1
            const float2 hi = __half22float2(kB[ki]);   // j2, j3
            // t = j&1: t0 -> (j0, j2), t1 -> (j1, j3)
            const float e0 = (t == 0 ? lo.x : lo.y) * simreg;
            const float e1 = (t == 0 ? hi.x : hi.y) * simreg;
            const int sp = ((ki * 2 + chalf) ^ xsw) << 1;
            *(float2*)&Tg[pos * 36 + sp] = make_float2(e0, e1);
        }
        __syncthreads();
        #pragma unroll
        for (int stp2 = 0; stp2 < 4; ++stp2) {
            const int flat = stp2 * 512 + tid;       // 0..2047
            const int qf16 = flat & 15;              // q quad 0..15
            const int pp   = (flat >> 4) & 127;
            const int hh = pp >> 5;
            const int ww = pp & 31;
            const int tile = qf16 >> 3;
            const int u    = qf16 & 7;               // q-local quad in tile
            const int xr   = (ww >> 2) & 7;
            const int p0   = (u << 1) ^ xr;          // physical f2 slot of pair0
            float4 o = *(const float4*)&shbuf[tile * 4608 + pp * 36 +
                                              ((p0 & ~1) << 1)];
            if (p0 & 1) o = make_float4(o.z, o.w, o.x, o.y);
            *(float4*)(out + (size_t)b * 131072 + (size_t)t * 65536 +
                       (size_t)(r0 + hh) * 2048 + ww * 64 + qf16 * 4) = o;
        }
        __syncthreads();
    }
}

extern "C" void kernel_launch(void* const* d_in, const int* in_sizes, int n_in,
                              void* d_out, int out_size, void* d_ws, size_t ws_size,
                              hipStream_t stream) {
    const float* p = (const float*)d_in[0];
    float* out = (float*)d_out;
    bcim_fused<<<dim3(2048), dim3(512), 0, stream>>>(p, out);
    (void)in_sizes; (void)n_in; (void)out_size; (void)d_ws; (void)ws_size;
}